// Round 11
// baseline (23.152 us; speedup 1.0000x reference)
//
#include <hip/hip_runtime.h>
#include <math.h>

#define NFACE 512
#define NVERT 642
#define NPIX  (256 * 256)
#define DXS   (2.0f / 256.0f)

// Camera constants (input-independent, folded from the reference):
#define EYEX 2.732f
#define EYEZ (-1.6728675276352845e-16f)
#define CC0  (6.123233995736766e-17f)

// ws layout (float4 units): tb0[512] | tb1[512] | tb2[512] | tb3[512]
// (SoA for coalescing), then bsum[1024] floats at float-offset 8192.
//   tb0=(A0,B0,C0,A1)  tb1=(B1,C1,DA,DB)  tb2=(DC,xmn,xmx,ymn)  tb3=(ymx,-,-,-)
// w_k = A_k*Py + B_k*Px + C_k  (== reference w_k/denom, sign folded),
// A2=-(A0+A1), B2=-(B0+B1), C2=1-C0-C1 (barycentrics sum to 1).
// depth = DA*Py + DB*Px + DC; inside => depth>0 (camera z in [1.73,3.73]).
// Degenerate faces: empty bbox (xmn=+3e30) -> always rejected.
__global__ __launch_bounds__(256) void setup_faces(
    const float* __restrict__ verts,   // (642,3)
    const int*   __restrict__ faces,   // (512,3)
    float* __restrict__ ws)
{
    int f = blockIdx.x * 256 + threadIdx.x;
    if (f >= NFACE) return;
    float4* tb0 = (float4*)ws;
    float4* tb1 = tb0 + NFACE;
    float4* tb2 = tb0 + 2 * NFACE;
    float4* tb3 = tb0 + 3 * NFACE;

    float vx[3], vy[3], vz[3];
#pragma unroll
    for (int k = 0; k < 3; ++k) {
        int vi = faces[f * 3 + k];
        float px = verts[vi * 3 + 0];
        float py = verts[vi * 3 + 1];
        float pz = verts[vi * 3 + 2];
        float dx = px - EYEX;
        float dz = pz - EYEZ;
        vx[k] = CC0 * dx + dz;
        vy[k] = py;
        vz[k] = -dx + CC0 * dz;
    }
    float ax = vx[0], ay = vy[0];
    float bx = vx[1], by = vy[1];
    float cx = vx[2], cy = vy[2];
    float denom = (bx - ax) * (cy - ay) - (by - ay) * (cx - ax);
    if (fabsf(denom) <= 1e-8f) {
        tb0[f] = make_float4(0.f, 0.f, 0.f, 0.f);
        tb1[f] = make_float4(0.f, 0.f, 0.f, 0.f);
        tb2[f] = make_float4(0.f, 3e30f, -3e30f, 3e30f);
        tb3[f] = make_float4(-3e30f, 0.f, 0.f, 0.f);
        return;
    }
    float si = 1.0f / denom;                  // sign folded
    float e0x = cx - bx, e0y = cy - by;
    float e1x = ax - cx, e1y = ay - cy;
    float A0 = e0x * si, B0 = -e0y * si, C0 = (e0y * bx - e0x * by) * si;
    float A1 = e1x * si, B1 = -e1y * si, C1 = (e1y * cx - e1x * cy) * si;
    float A2 = -(A0 + A1), B2 = -(B0 + B1), C2 = 1.0f - C0 - C1;
    float DA = A0 * vz[0] + A1 * vz[1] + A2 * vz[2];
    float DB = B0 * vz[0] + B1 * vz[1] + B2 * vz[2];
    float DC = C0 * vz[0] + C1 * vz[1] + C2 * vz[2];
    float xmn = fminf(fminf(ax, bx), cx), xmx = fmaxf(fmaxf(ax, bx), cx);
    float ymn = fminf(fminf(ay, by), cy), ymx = fmaxf(fmaxf(ay, by), cy);

    tb0[f] = make_float4(A0, B0, C0, A1);
    tb1[f] = make_float4(B1, C1, DA, DB);
    tb2[f] = make_float4(DC, xmn, xmx, ymn);
    tb3[f] = make_float4(ymx, 0.f, 0.f, 0.f);
}

// One 8x8 tile per 64-thread block (1024 blocks, ~4/CU). Classify all 512
// faces vs the tile via exact corner bounds (class+dmin kept in registers
// across the M barrier), per-tile depth prune (M = min over full-inside
// faces of dmax+md; any face with dmin-md > M cannot win the argmin
// anywhere in the tile — pruning only removes reference-losing faces),
// append survivors to LDS lists, then per-pixel argmin + epilogue.
// Argmin pack: (depth_bits & ~511) | face, u32 min — order-invariant,
// ties -> smaller face index (matches jnp.argmin first-index).
__global__ __launch_bounds__(64) void render_tile(
    const float4* __restrict__ tb,     // SoA table base
    const float* __restrict__ tex,     // (512,4,4,4,3)
    const float* __restrict__ ref,     // (3,256,256)
    float* __restrict__ bsum)          // (1024) per-block partial sums
{
    __shared__ float4 flist[NFACE];      // full: DA,DB,DC,fid
    __shared__ float4 plist[NFACE][3];   // partial: q0,q1,(DC,fid,-,-)
    __shared__ int fcnt, pcnt;
    __shared__ unsigned Mu;

    const float4* tb0 = tb;
    const float4* tb1 = tb + NFACE;
    const float4* tb2 = tb + 2 * NFACE;
    const float4* tb3 = tb + 3 * NFACE;

    int lane = threadIdx.x;
    if (lane == 0) { fcnt = 0; pcnt = 0; Mu = 0x7f800000u; }
    __syncthreads();

    int tileX = (blockIdx.x & 31) << 3;
    int tileY = (blockIdx.x >> 5) << 3;
    float xlo = (tileX + 0.5f) * DXS - 1.0f;
    float xhi = (tileX + 7.5f) * DXS - 1.0f;
    float yhi = 1.0f - (tileY + 0.5f) * DXS;
    float ylo = 1.0f - (tileY + 7.5f) * DXS;

    // ---- pass A: classify 8 faces/lane, results in registers ----
    int   rcls[8];       // 0=reject, 1=full, 2=partial
    float rdmn[8];       // dmin - margin
#pragma unroll
    for (int r = 0; r < 8; ++r) {
        int f = r * 64 + lane;
        rcls[r] = 0;
        float4 q2 = tb2[f];
        float4 q3 = tb3[f];
        if ((q2.y > xhi + 1e-5f) | (q2.z < xlo - 1e-5f) |
            (q2.w > yhi + 1e-5f) | (q3.x < ylo - 1e-5f)) continue;
        float4 q0 = tb0[f];
        float4 q1 = tb1[f];
        float A0 = q0.x, B0 = q0.y, C0 = q0.z, A1 = q0.w, B1 = q1.x, C1 = q1.y;
        float DA = q1.z, DB = q1.w, DC = q2.x;
        float A2 = -(A0 + A1), B2 = -(B0 + B1), C2 = 1.0f - C0 - C1;
        float As[3] = {A0, A1, A2}, Bs[3] = {B0, B1, B2}, Cs[3] = {C0, C1, C2};
        bool rej = false, full = true;
#pragma unroll
        for (int k = 0; k < 3; ++k) {
            float ta = As[k] * ylo, tb_ = As[k] * yhi;
            float ua = Bs[k] * xlo, ub = Bs[k] * xhi;
            float wmx = fmaxf(ta, tb_) + fmaxf(ua, ub) + Cs[k];
            float wmn = fminf(ta, tb_) + fminf(ua, ub) + Cs[k];
            float mg  = (fabsf(As[k]) + fabsf(Bs[k]) + fabsf(Cs[k])) * 2e-6f;
            rej  = rej  | (wmx < -mg);
            full = full & (wmn > mg);
        }
        if (rej) continue;
        float da = DA * ylo, db = DA * yhi;
        float ea = DB * xlo, eb = DB * xhi;
        float dmx = fmaxf(da, db) + fmaxf(ea, eb) + DC;
        float dmn = fminf(da, db) + fminf(ea, eb) + DC;
        float md  = (fabsf(DA) + fabsf(DB) + fabsf(DC)) * 2e-6f + 1e-4f;
        rdmn[r] = dmn - md;
        rcls[r] = full ? 1 : 2;
        if (full) atomicMin(&Mu, __float_as_uint(dmx + md));
    }
    __syncthreads();
    float M = __uint_as_float(Mu);

    // ---- pass B: depth-pruned append (reload coefs, L1-hot) ----
#pragma unroll
    for (int r = 0; r < 8; ++r) {
        if (rcls[r] == 0 || rdmn[r] > M) continue;
        int f = r * 64 + lane;
        float4 q0 = tb0[f];
        float4 q1 = tb1[f];
        float4 q2 = tb2[f];
        float fb = __uint_as_float((unsigned)f);
        if (rcls[r] == 1) {
            int s = atomicAdd(&fcnt, 1);
            flist[s] = make_float4(q1.z, q1.w, q2.x, fb);
        } else {
            int s = atomicAdd(&pcnt, 1);
            plist[s][0] = q0;
            plist[s][1] = q1;
            plist[s][2] = make_float4(q2.x, fb, 0.f, 0.f);
        }
    }
    __syncthreads();
    int fc = fcnt, pc = pcnt;

    // ---- pass C: per-pixel argmin (batched LDS broadcasts) ----
    int i = tileX + (lane & 7);
    int j = tileY + (lane >> 3);
    float Px = (i + 0.5f) * DXS - 1.0f;
    float Py = 1.0f - (j + 0.5f) * DXS;

    unsigned best = 0xFFFFFFFFu;
    int k = 0;
    for (; k + 4 <= fc; k += 4) {
        float4 ra = flist[k + 0], rb = flist[k + 1];
        float4 rc = flist[k + 2], rd = flist[k + 3];
        float da = fmaf(ra.x, Py, fmaf(ra.y, Px, ra.z));
        float db = fmaf(rb.x, Py, fmaf(rb.y, Px, rb.z));
        float dc = fmaf(rc.x, Py, fmaf(rc.y, Px, rc.z));
        float dd = fmaf(rd.x, Py, fmaf(rd.y, Px, rd.z));
        unsigned ca = (__float_as_uint(da) & 0xFFFFFE00u) | __float_as_uint(ra.w);
        unsigned cb = (__float_as_uint(db) & 0xFFFFFE00u) | __float_as_uint(rb.w);
        unsigned cc = (__float_as_uint(dc) & 0xFFFFFE00u) | __float_as_uint(rc.w);
        unsigned cd = (__float_as_uint(dd) & 0xFFFFFE00u) | __float_as_uint(rd.w);
        ca = ca < cb ? ca : cb;
        cc = cc < cd ? cc : cd;
        ca = ca < cc ? ca : cc;
        best = best < ca ? best : ca;
    }
    for (; k < fc; ++k) {
        float4 r = flist[k];
        float dep = fmaf(r.x, Py, fmaf(r.y, Px, r.z));
        unsigned cand = (__float_as_uint(dep) & 0xFFFFFE00u) | __float_as_uint(r.w);
        best = best < cand ? best : cand;
    }
    k = 0;
    for (; k + 2 <= pc; k += 2) {
        float4 a0 = plist[k][0], a1 = plist[k][1], a2 = plist[k][2];
        float4 b0 = plist[k+1][0], b1 = plist[k+1][1], b2 = plist[k+1][2];
        float aw0 = fmaf(a0.x, Py, fmaf(a0.y, Px, a0.z));
        float aw1 = fmaf(a0.w, Py, fmaf(a1.x, Px, a1.y));
        float aw2 = 1.0f - aw0 - aw1;
        float adp = fmaf(a1.z, Py, fmaf(a1.w, Px, a2.x));
        float amn = fminf(fminf(aw0, aw1), aw2);
        unsigned ac = (__float_as_uint(adp) & 0xFFFFFE00u) | __float_as_uint(a2.y);
        ac = (amn >= 0.f) ? ac : 0xFFFFFFFFu;
        float bw0 = fmaf(b0.x, Py, fmaf(b0.y, Px, b0.z));
        float bw1 = fmaf(b0.w, Py, fmaf(b1.x, Px, b1.y));
        float bw2 = 1.0f - bw0 - bw1;
        float bdp = fmaf(b1.z, Py, fmaf(b1.w, Px, b2.x));
        float bmn = fminf(fminf(bw0, bw1), bw2);
        unsigned bc = (__float_as_uint(bdp) & 0xFFFFFE00u) | __float_as_uint(b2.y);
        bc = (bmn >= 0.f) ? bc : 0xFFFFFFFFu;
        ac = ac < bc ? ac : bc;
        best = best < ac ? best : ac;
    }
    for (; k < pc; ++k) {
        float4 q0 = plist[k][0], q1 = plist[k][1], q2 = plist[k][2];
        float w0  = fmaf(q0.x, Py, fmaf(q0.y, Px, q0.z));
        float w1  = fmaf(q0.w, Py, fmaf(q1.x, Px, q1.y));
        float w2  = 1.0f - w0 - w1;
        float dep = fmaf(q1.z, Py, fmaf(q1.w, Px, q2.x));
        float mn  = fminf(fminf(w0, w1), w2);
        unsigned cand = (__float_as_uint(dep) & 0xFFFFFE00u) | __float_as_uint(q2.y);
        cand = (mn >= 0.f) ? cand : 0xFFFFFFFFu;
        best = best < cand ? best : cand;
    }

    // ---- epilogue ----
    int p = j * 256 + i;
    float col0 = 0.f, col1 = 0.f, col2 = 0.f;
    if (best != 0xFFFFFFFFu) {
        int bf = (int)(best & 511u);
        float4 q0 = tb0[bf];
        float4 q1 = tb1[bf];
        float w0 = fmaf(q0.x, Py, fmaf(q0.y, Px, q0.z));
        float w1 = fmaf(q0.w, Py, fmaf(q1.x, Px, q1.y));
        float w2 = 1.0f - w0 - w1;
        int t0 = (int)rintf(w0 * 3.0f); t0 = t0 < 0 ? 0 : (t0 > 3 ? 3 : t0);
        int t1 = (int)rintf(w1 * 3.0f); t1 = t1 < 0 ? 0 : (t1 > 3 ? 3 : t1);
        int t2 = (int)rintf(w2 * 3.0f); t2 = t2 < 0 ? 0 : (t2 > 3 ? 3 : t2);
        const float* tp = tex + ((((bf * 4 + t0) * 4 + t1) * 4 + t2) * 3);
        col0 = tanhf(tp[0]);
        col1 = tanhf(tp[1]);
        col2 = tanhf(tp[2]);
    }
    float r0 = ref[0 * NPIX + p];
    float r1 = ref[1 * NPIX + p];
    float r2 = ref[2 * NPIX + p];
    float e0 = col0 - r0, e1 = col1 - r1, e2 = col2 - r2;
    float loss = e0 * e0 + e1 * e1 + e2 * e2;

    // ---- wave reduce, plain store (no atomics) ----
    for (int off = 32; off > 0; off >>= 1)
        loss += __shfl_down(loss, off, 64);
    if (lane == 0) bsum[blockIdx.x] = loss;
}

__global__ __launch_bounds__(256) void finalize(
    const float* __restrict__ bsum,    // (1024)
    float* __restrict__ out)
{
    __shared__ float wsum[4];
    int tid = threadIdx.x;
    float v = bsum[tid] + bsum[tid + 256] + bsum[tid + 512] + bsum[tid + 768];
    for (int off = 32; off > 0; off >>= 1)
        v += __shfl_down(v, off, 64);
    int lane = tid & 63;
    int wid  = tid >> 6;
    if (lane == 0) wsum[wid] = v;
    __syncthreads();
    if (tid == 0) out[0] = wsum[0] + wsum[1] + wsum[2] + wsum[3];
}

extern "C" void kernel_launch(void* const* d_in, const int* in_sizes, int n_in,
                              void* d_out, int out_size, void* d_ws, size_t ws_size,
                              hipStream_t stream) {
    const float* verts = (const float*)d_in[0];
    const float* tex   = (const float*)d_in[1];
    const float* ref   = (const float*)d_in[2];
    const int*   faces = (const int*)d_in[3];
    float* out = (float*)d_out;
    float* ws  = (float*)d_ws;   // table (32 KB) + bsum (4 KB)

    setup_faces<<<2, 256, 0, stream>>>(verts, faces, ws);
    render_tile<<<1024, 64, 0, stream>>>((const float4*)ws, tex, ref, ws + 8192);
    finalize<<<1, 256, 0, stream>>>(ws + 8192, out);
}

// Round 12
// 21.454 us; speedup vs baseline: 1.0792x; 1.0792x over previous
//
#include <hip/hip_runtime.h>
#include <math.h>

#define NFACE 512
#define NVERT 642
#define NPIX  (256 * 256)
#define DXS   (2.0f / 256.0f)

// Camera constants (input-independent, folded from the reference):
#define EYEX 2.732f
#define EYEZ (-1.6728675276352845e-16f)
#define CC0  (6.123233995736766e-17f)

// Fused renderer, 256 blocks x 256 threads, block = 16x16 tile, wave = one
// 8x8 quadrant. Pass A: each thread sets up 2 faces into LDS tables and
// classifies them against all 4 quadrants via center-form bounds
// (w(center) +- (|A|+|B|)*3.5*DXS — affine => exact), with per-quadrant
// depth range; full faces atomicMin a per-quadrant M = min(dmax+md).
// Pass B: ballot per (face-word, quadrant) -> full/partial masks in LDS
// (prune: dmin-md > M_s can never win the argmin in quadrant s — removes
// only reference-losing faces). Pass B2: each wave ballot-compacts its own
// masks to index lists. Pass C: R10-style batched argmin over the wave's
// lists. Pack (depth_bits & ~511) | face, u32 min — order-invariant,
// ties -> smaller face index (matches jnp.argmin first-index).
// Records: w_k = A_k*Py+B_k*Px+C_k (== ref w_k/denom, sign folded),
// w2 = 1-w0-w1; depth = DA*Py+DB*Px+DC; inside => depth>0 (camera z>1.7).
__global__ __launch_bounds__(256) void render_loss(
    const float* __restrict__ verts,   // (642,3)
    const int*   __restrict__ faces,   // (512,3)
    const float* __restrict__ tex,     // (512,4,4,4,3)
    const float* __restrict__ ref,     // (3,256,256)
    float* __restrict__ out)           // scalar (pre-zeroed)
{
    __shared__ float  sverts[NVERT * 3];
    __shared__ float4 sf0[NFACE];            // A0,B0,C0,A1
    __shared__ float4 sf1[NFACE];            // B1,C1,DA,DB
    __shared__ float4 sdep[NFACE];           // DA,DB,DC,fid_bits
    __shared__ unsigned long long fmask[4][8], pmask[4][8];
    __shared__ unsigned Mu[4];
    __shared__ unsigned fidx[4][NFACE], pidx[4][NFACE];
    __shared__ float wsum[4];

    int tid  = threadIdx.x;
    int lane = tid & 63;
    int w    = tid >> 6;
    if (tid < 4) Mu[tid] = 0x7f800000u;

    for (int k = tid; k < NVERT * 3; k += 256) sverts[k] = verts[k];
    __syncthreads();

    int tileX = (blockIdx.x & 15) << 4;
    int tileY = (blockIdx.x >> 4) << 4;
    float xlo = (tileX + 0.5f)  * DXS - 1.0f;
    float xhi = (tileX + 15.5f) * DXS - 1.0f;
    float yhi = 1.0f - (tileY + 0.5f)  * DXS;
    float ylo = 1.0f - (tileY + 15.5f) * DXS;
    float xcm = 0.5f * (xlo + xhi);          // tile center
    float ycm = 0.5f * (ylo + yhi);
    const float H  = 3.5f * DXS;             // quadrant half-extent
    const float Q  = 4.0f * DXS;             // quadrant center offset

    // ---- pass A: setup + 4-quadrant classify (2 faces/thread) ----
    unsigned cls = 0;                        // 2 bits per (it*4+s)
    float dmn8[8];
#pragma unroll
    for (int it = 0; it < 2; ++it) {
        int f = tid + it * 256;
        float vx[3], vy[3], vz[3];
#pragma unroll
        for (int k = 0; k < 3; ++k) {
            int vi = faces[f * 3 + k];
            float px = sverts[vi * 3 + 0];
            float py = sverts[vi * 3 + 1];
            float pz = sverts[vi * 3 + 2];
            float dx = px - EYEX;
            float dz = pz - EYEZ;
            vx[k] = CC0 * dx + dz;
            vy[k] = py;
            vz[k] = -dx + CC0 * dz;
        }
        float ax = vx[0], ay = vy[0];
        float bx = vx[1], by = vy[1];
        float cx = vx[2], cy = vy[2];
        float denom = (bx - ax) * (cy - ay) - (by - ay) * (cx - ax);
        bool ok = fabsf(denom) > 1e-8f;
        float si = ok ? (1.0f / denom) : 0.0f;
        float e0x = cx - bx, e0y = cy - by;
        float e1x = ax - cx, e1y = ay - cy;
        float A0 = e0x * si, B0 = -e0y * si, C0 = (e0y * bx - e0x * by) * si;
        float A1 = e1x * si, B1 = -e1y * si, C1 = (e1y * cx - e1x * cy) * si;
        float A2 = -(A0 + A1), B2 = -(B0 + B1), C2 = 1.0f - C0 - C1;
        float DA = A0 * vz[0] + A1 * vz[1] + A2 * vz[2];
        float DB = B0 * vz[0] + B1 * vz[1] + B2 * vz[2];
        float DC = C0 * vz[0] + C1 * vz[1] + C2 * vz[2];
        sf0[f]  = make_float4(A0, B0, C0, A1);
        sf1[f]  = make_float4(B1, C1, DA, DB);
        sdep[f] = make_float4(DA, DB, DC, __uint_as_float((unsigned)f));
        if (!ok) continue;

        float bxmn = fminf(fminf(ax, bx), cx), bxmx = fmaxf(fmaxf(ax, bx), cx);
        float bymn = fminf(fminf(ay, by), cy), bymx = fmaxf(fmaxf(ay, by), cy);
        if ((bxmn > xhi + 1e-5f) | (bxmx < xlo - 1e-5f) |
            (bymn > yhi + 1e-5f) | (bymx < ylo - 1e-5f)) continue;

        float As[3] = {A0, A1, A2}, Bs[3] = {B0, B1, B2}, Cs[3] = {C0, C1, C2};
        float wc[3], Aq[3], Bq[3], ee[3], mg[3];
#pragma unroll
        for (int k = 0; k < 3; ++k) {
            wc[k] = fmaf(As[k], ycm, fmaf(Bs[k], xcm, Cs[k]));
            Aq[k] = As[k] * Q;
            Bq[k] = Bs[k] * Q;
            ee[k] = (fabsf(As[k]) + fabsf(Bs[k])) * H;
            mg[k] = (fabsf(As[k]) + fabsf(Bs[k]) + fabsf(Cs[k])) * 4e-6f;
        }
        float dc  = fmaf(DA, ycm, fmaf(DB, xcm, DC));
        float DAq = DA * Q, DBq = DB * Q;
        float de  = (fabsf(DA) + fabsf(DB)) * H;
        float md  = (fabsf(DA) + fabsf(DB) + fabsf(DC)) * 4e-6f + 1e-4f;

#pragma unroll
        for (int s = 0; s < 4; ++s) {
            float fx = (s & 1) ? 1.0f : -1.0f;   // x offset sign
            float fy = (s & 2) ? -1.0f : 1.0f;   // y: sy=0 top (+)
            bool rej = false, full = true;
#pragma unroll
            for (int k = 0; k < 3; ++k) {
                float wcs = wc[k] + fy * Aq[k] + fx * Bq[k];
                rej  = rej  | (wcs + ee[k] < -mg[k]);
                full = full & (wcs - ee[k] >  mg[k]);
            }
            if (rej) continue;
            float dcs = dc + fy * DAq + fx * DBq;
            dmn8[it * 4 + s] = dcs - de - md;
            cls |= (full ? 1u : 2u) << (2 * (it * 4 + s));
            if (full) atomicMin(&Mu[s], __float_as_uint(dcs + de + md));
        }
    }
    __syncthreads();

    // ---- pass B: pruned ballots -> masks ----
    float Ms0 = __uint_as_float(Mu[0]), Ms1 = __uint_as_float(Mu[1]);
    float Ms2 = __uint_as_float(Mu[2]), Ms3 = __uint_as_float(Mu[3]);
    float Ms[4] = {Ms0, Ms1, Ms2, Ms3};
#pragma unroll
    for (int it = 0; it < 2; ++it) {
#pragma unroll
        for (int s = 0; s < 4; ++s) {
            unsigned c = (cls >> (2 * (it * 4 + s))) & 3u;
            bool alive = (c != 0u) && (dmn8[it * 4 + s] <= Ms[s]);
            unsigned long long bf = __ballot(alive && (c == 1u));
            unsigned long long bp = __ballot(alive && (c == 2u));
            if (lane == 0) {
                fmask[s][it * 4 + w] = bf;
                pmask[s][it * 4 + w] = bp;
            }
        }
    }
    __syncthreads();

    // ---- pass B2: each wave compacts its quadrant's masks ----
    unsigned long long ltm = (1ull << lane) - 1ull;
    int fc = 0, pc = 0;
#pragma unroll
    for (int jj = 0; jj < 8; ++jj) {
        unsigned long long m = fmask[w][jj];
        if ((m >> lane) & 1ull) fidx[w][fc + (int)__popcll(m & ltm)] = jj * 64 + lane;
        fc += (int)__popcll(m);
        m = pmask[w][jj];
        if ((m >> lane) & 1ull) pidx[w][pc + (int)__popcll(m & ltm)] = jj * 64 + lane;
        pc += (int)__popcll(m);
    }

    // ---- pass C: per-pixel argmin over the wave's lists ----
    int i = tileX + ((w & 1) << 3) + (lane & 7);
    int j = tileY + ((w >> 1) << 3) + (lane >> 3);
    float Px = (i + 0.5f) * DXS - 1.0f;
    float Py = 1.0f - (j + 0.5f) * DXS;

    unsigned best = 0xFFFFFFFFu;
    int k = 0;
    for (; k + 4 <= fc; k += 4) {
        uint4 id = *(const uint4*)&fidx[w][k];
        float4 ra = sdep[id.x], rb = sdep[id.y];
        float4 rc = sdep[id.z], rd = sdep[id.w];
        float da = fmaf(ra.x, Py, fmaf(ra.y, Px, ra.z));
        float db = fmaf(rb.x, Py, fmaf(rb.y, Px, rb.z));
        float dc = fmaf(rc.x, Py, fmaf(rc.y, Px, rc.z));
        float dd = fmaf(rd.x, Py, fmaf(rd.y, Px, rd.z));
        unsigned ca = (__float_as_uint(da) & 0xFFFFFE00u) | __float_as_uint(ra.w);
        unsigned cb = (__float_as_uint(db) & 0xFFFFFE00u) | __float_as_uint(rb.w);
        unsigned cc = (__float_as_uint(dc) & 0xFFFFFE00u) | __float_as_uint(rc.w);
        unsigned cd = (__float_as_uint(dd) & 0xFFFFFE00u) | __float_as_uint(rd.w);
        ca = ca < cb ? ca : cb;
        cc = cc < cd ? cc : cd;
        ca = ca < cc ? ca : cc;
        best = best < ca ? best : ca;
    }
    for (; k < fc; ++k) {
        float4 r = sdep[fidx[w][k]];
        float dep = fmaf(r.x, Py, fmaf(r.y, Px, r.z));
        unsigned cand = (__float_as_uint(dep) & 0xFFFFFE00u) | __float_as_uint(r.w);
        best = best < cand ? best : cand;
    }
    k = 0;
    for (; k + 2 <= pc; k += 2) {
        uint2 id = *(const uint2*)&pidx[w][k];
        float4 a0 = sf0[id.x], a1 = sf1[id.x], a2 = sdep[id.x];
        float4 b0 = sf0[id.y], b1 = sf1[id.y], b2 = sdep[id.y];
        float aw0 = fmaf(a0.x, Py, fmaf(a0.y, Px, a0.z));
        float aw1 = fmaf(a0.w, Py, fmaf(a1.x, Px, a1.y));
        float aw2 = 1.0f - aw0 - aw1;
        float adp = fmaf(a2.x, Py, fmaf(a2.y, Px, a2.z));
        float amn = fminf(fminf(aw0, aw1), aw2);
        unsigned ac = (__float_as_uint(adp) & 0xFFFFFE00u) | __float_as_uint(a2.w);
        ac = (amn >= 0.f) ? ac : 0xFFFFFFFFu;
        float bw0 = fmaf(b0.x, Py, fmaf(b0.y, Px, b0.z));
        float bw1 = fmaf(b0.w, Py, fmaf(b1.x, Px, b1.y));
        float bw2 = 1.0f - bw0 - bw1;
        float bdp = fmaf(b2.x, Py, fmaf(b2.y, Px, b2.z));
        float bmn = fminf(fminf(bw0, bw1), bw2);
        unsigned bc = (__float_as_uint(bdp) & 0xFFFFFE00u) | __float_as_uint(b2.w);
        bc = (bmn >= 0.f) ? bc : 0xFFFFFFFFu;
        ac = ac < bc ? ac : bc;
        best = best < ac ? best : ac;
    }
    for (; k < pc; ++k) {
        unsigned idx = pidx[w][k];
        float4 q0 = sf0[idx], q1 = sf1[idx], q2 = sdep[idx];
        float w0  = fmaf(q0.x, Py, fmaf(q0.y, Px, q0.z));
        float w1  = fmaf(q0.w, Py, fmaf(q1.x, Px, q1.y));
        float w2  = 1.0f - w0 - w1;
        float dep = fmaf(q2.x, Py, fmaf(q2.y, Px, q2.z));
        float mn  = fminf(fminf(w0, w1), w2);
        unsigned cand = (__float_as_uint(dep) & 0xFFFFFE00u) | __float_as_uint(q2.w);
        cand = (mn >= 0.f) ? cand : 0xFFFFFFFFu;
        best = best < cand ? best : cand;
    }

    // ---- epilogue ----
    int p = j * 256 + i;
    float col0 = 0.f, col1 = 0.f, col2 = 0.f;
    if (best != 0xFFFFFFFFu) {
        int bf = (int)(best & 511u);
        float4 q0 = sf0[bf];
        float4 q1 = sf1[bf];
        float w0 = fmaf(q0.x, Py, fmaf(q0.y, Px, q0.z));
        float w1 = fmaf(q0.w, Py, fmaf(q1.x, Px, q1.y));
        float w2 = 1.0f - w0 - w1;
        int t0 = (int)rintf(w0 * 3.0f); t0 = t0 < 0 ? 0 : (t0 > 3 ? 3 : t0);
        int t1 = (int)rintf(w1 * 3.0f); t1 = t1 < 0 ? 0 : (t1 > 3 ? 3 : t1);
        int t2 = (int)rintf(w2 * 3.0f); t2 = t2 < 0 ? 0 : (t2 > 3 ? 3 : t2);
        const float* tp = tex + ((((bf * 4 + t0) * 4 + t1) * 4 + t2) * 3);
        col0 = tanhf(tp[0]);
        col1 = tanhf(tp[1]);
        col2 = tanhf(tp[2]);
    }
    float r0 = ref[0 * NPIX + p];
    float r1 = ref[1 * NPIX + p];
    float r2 = ref[2 * NPIX + p];
    float e0 = col0 - r0, e1 = col1 - r1, e2 = col2 - r2;
    float loss = e0 * e0 + e1 * e1 + e2 * e2;

    for (int off = 32; off > 0; off >>= 1)
        loss += __shfl_down(loss, off, 64);
    if (lane == 0) wsum[w] = loss;
    __syncthreads();
    if (tid == 0)
        atomicAdd(out, wsum[0] + wsum[1] + wsum[2] + wsum[3]);
}

extern "C" void kernel_launch(void* const* d_in, const int* in_sizes, int n_in,
                              void* d_out, int out_size, void* d_ws, size_t ws_size,
                              hipStream_t stream) {
    const float* verts = (const float*)d_in[0];
    const float* tex   = (const float*)d_in[1];
    const float* ref   = (const float*)d_in[2];
    const int*   faces = (const int*)d_in[3];
    float* out = (float*)d_out;

    hipMemsetAsync(out, 0, sizeof(float), stream);
    render_loss<<<256, 256, 0, stream>>>(verts, faces, tex, ref, out);
}